// Round 5
// baseline (52.760 us; speedup 1.0000x reference)
//
#include <hip/hip_runtime.h>
#include <float.h>

#define NL 32
#define NT 16384
#define NE 64
#define NK 8
#define LOG2E 1.4426950408889634f

// DPP control codes
#define DPP_QUAD_XOR1 0xB1   // quad_perm [1,0,3,2]
#define DPP_QUAD_XOR2 0x4E   // quad_perm [2,3,0,1]
#define DPP_ROW_ROR4  0x124  // row_ror:4
#define DPP_ROW_ROR8  0x128  // row_ror:8

template <int CTRL>
__device__ __forceinline__ float dppmv(float v) {
    return __int_as_float(
        __builtin_amdgcn_update_dpp(0, __float_as_int(v), CTRL, 0xF, 0xF, true));
}

// reduce across a 16-lane group (DPP row = 16 lanes on CDNA)
__device__ __forceinline__ float grp_max(float v) {
    v = fmaxf(v, dppmv<DPP_QUAD_XOR1>(v));
    v = fmaxf(v, dppmv<DPP_QUAD_XOR2>(v));
    v = fmaxf(v, dppmv<DPP_ROW_ROR4>(v));
    v = fmaxf(v, dppmv<DPP_ROW_ROR8>(v));
    return v;
}
__device__ __forceinline__ float grp_sum(float v) {
    v = v + dppmv<DPP_QUAD_XOR1>(v);
    v = v + dppmv<DPP_QUAD_XOR2>(v);
    v = v + dppmv<DPP_ROW_ROR4>(v);
    v = v + dppmv<DPP_ROW_ROR8>(v);
    return v;
}

// descending compare-exchange
__device__ __forceinline__ void ce(float& a, float& b) {
    float hi = fmaxf(a, b);
    float lo = fminf(a, b);
    a = hi; b = lo;
}

__global__ __launch_bounds__(256, 8) void bl_main(const float* __restrict__ logits,
                                                  float* __restrict__ g_w,
                                                  float* __restrict__ g_c) {
    const int tid  = threadIdx.x;
    const int lane = tid & 63;
    const int wv   = tid >> 6;
    const long slab = ((long)blockIdx.x * 4 + wv) * 64;  // first token of this wave
    const int layer = (int)(slab >> 14);                 // 16384 tokens per layer

    // Coalesced loads: float4 chunk index j*64+lane (1KB/instr). Lane i holds
    // experts (i&15)*4..+3 of token slab + 4j + (i>>4).
    const float4* p = (const float4*)(logits + slab * NE);

    float wacc[4] = {0.f, 0.f, 0.f, 0.f};
    float cacc[4] = {0.f, 0.f, 0.f, 0.f};

    // 2-deep rolling prefetch ring; all indices static after full unroll
    float4 buf[2];
    buf[0] = p[0 * 64 + lane];
    buf[1] = p[1 * 64 + lane];

#pragma unroll
    for (int j = 0; j < 16; ++j) {
        const float4 cur = buf[j & 1];
        if (j + 2 < 16) buf[j & 1] = p[(j + 2) * 64 + lane];

        // exp-space immediately (monotone -> same top-k selection, fewer live regs)
        const float x0 = __builtin_amdgcn_exp2f(cur.x * LOG2E);
        const float x1 = __builtin_amdgcn_exp2f(cur.y * LOG2E);
        const float x2 = __builtin_amdgcn_exp2f(cur.z * LOG2E);
        const float x3 = __builtin_amdgcn_exp2f(cur.w * LOG2E);

        const float den = grp_sum((x0 + x1) + (x2 + x3));
        const float inv = __builtin_amdgcn_rcpf(den);

        // lane-local sorted queue (desc) of its 4 exp-values
        float q0 = x0, q1 = x1, q2 = x2, q3 = x3;
        ce(q0, q1); ce(q2, q3); ce(q0, q2); ce(q1, q3); ce(q1, q2);

        // 8 pop rounds across the 16-lane group -> threshold = 8th largest of 64
        float thr = 0.f;
#pragma unroll
        for (int k = 0; k < NK; ++k) {
            const float m = grp_max(q0);
            thr = m;
            if (k < NK - 1) {
                const bool hit = (q0 == m);
                q0 = hit ? q1 : q0;
                q1 = hit ? q2 : q1;
                q2 = hit ? q3 : q2;
                q3 = hit ? -1.0f : q3;   // x >= 0 always, so -1 is a safe sentinel
            }
        }

        // top-k membership counts (lane-local experts), in exp-space
        cacc[0] += (x0 >= thr) ? 1.f : 0.f;
        cacc[1] += (x1 >= thr) ? 1.f : 0.f;
        cacc[2] += (x2 >= thr) ? 1.f : 0.f;
        cacc[3] += (x3 >= thr) ? 1.f : 0.f;

        // softmax weight accumulation
        wacc[0] = fmaf(x0, inv, wacc[0]);
        wacc[1] = fmaf(x1, inv, wacc[1]);
        wacc[2] = fmaf(x2, inv, wacc[2]);
        wacc[3] = fmaf(x3, inv, wacc[3]);
    }

    // combine the 4 groups of the wave (lanes with equal (lane&15) share experts)
#pragma unroll
    for (int r = 0; r < 4; ++r) {
        wacc[r] += __shfl_xor(wacc[r], 16);
        wacc[r] += __shfl_xor(wacc[r], 32);
        cacc[r] += __shfl_xor(cacc[r], 16);
        cacc[r] += __shfl_xor(cacc[r], 32);
    }

    // block-level combine in LDS, then one batch of atomics per block
    __shared__ float comb[2][NE][4];
    if (lane < 16) {
#pragma unroll
        for (int r = 0; r < 4; ++r) {
            comb[0][lane * 4 + r][wv] = wacc[r];
            comb[1][lane * 4 + r][wv] = cacc[r];
        }
    }
    __syncthreads();
    if (tid < 128) {
        const int s = tid >> 6, e = tid & 63;
        const float val = comb[s][e][0] + comb[s][e][1] + comb[s][e][2] + comb[s][e][3];
        float* dst = s ? g_c : g_w;
        atomicAdd(&dst[layer * NE + e], val);
    }
}

__global__ void bl_final(const float* __restrict__ g_w,
                         const float* __restrict__ g_c,
                         float* __restrict__ out) {
    __shared__ float red[256];
    float p = 0.f;
    for (int i = threadIdx.x; i < NL * NE; i += 256) p += g_c[i] * g_w[i];
    red[threadIdx.x] = p;
    __syncthreads();
    for (int s = 128; s > 0; s >>= 1) {
        if (threadIdx.x < s) red[threadIdx.x] += red[threadIdx.x + s];
        __syncthreads();
    }
    if (threadIdx.x == 0) {
        // loss = 0.01 * sum_l[ (E/(T*K)) * sum_e counts * (wsum/T) ]
        const float factor = (float)(0.01 * ((double)NE / ((double)NT * NK)) / (double)NT);
        out[0] = red[0] * factor;
    }
}

extern "C" void kernel_launch(void* const* d_in, const int* in_sizes, int n_in,
                              void* d_out, int out_size, void* d_ws, size_t ws_size,
                              hipStream_t stream) {
    const float* logits = (const float*)d_in[0];
    float* g_w = (float*)d_ws;            // [NL*NE] softmax weight sums
    float* g_c = g_w + NL * NE;           // [NL*NE] top-k counts (as float)

    hipMemsetAsync(d_ws, 0, 2 * NL * NE * sizeof(float), stream);
    bl_main<<<dim3(2048), dim3(256), 0, stream>>>(logits, g_w, g_c);
    bl_final<<<dim3(1), dim3(256), 0, stream>>>(g_w, g_c, (float*)d_out);
}